// Round 10
// baseline (184.893 us; speedup 1.0000x reference)
//
#include <hip/hip_runtime.h>

#define HD 256
#define LN_EPS 1e-5f
#define DEG_EPS 1e-6f
#define CAP 64
#define C1 264   // LDS row pitch in shorts for 64-row tile buffers

typedef __attribute__((ext_vector_type(8))) short short8;
typedef __attribute__((ext_vector_type(4))) short s16x4;
typedef __attribute__((ext_vector_type(4))) float f32x4;

__device__ inline unsigned short f2bf(float f) {
    union { float f; unsigned int u; } v; v.f = f;
    unsigned int r = v.u + 0x7FFFu + ((v.u >> 16) & 1u);
    return (unsigned short)(r >> 16);
}
__device__ inline float bf2f(unsigned short h) {
    union { unsigned int u; float f; } v; v.u = ((unsigned int)h) << 16;
    return v.f;
}

// Convert weight matrices to bf16 once per launch (deterministic, tiny).
__global__ void prep_kernel(const float* __restrict__ msg_W,
                            const float* __restrict__ upd_W,
                            unsigned short* __restrict__ w1b,
                            unsigned short* __restrict__ w2b,
                            float* __restrict__ ucol) {
    int t = blockIdx.x * blockDim.x + threadIdx.x;
    if (t < 256 * 256) {
        w1b[t] = f2bf(msg_W[t]);
        int j = t >> 8, k = t & 255;
        w2b[t] = f2bf(upd_W[j * 257 + k]);
        if (k == 0) ucol[j] = upd_W[j * 257 + 256];
    }
}

// Bucket edges by dst: counts[] = degree, eidx[d*CAP + p] = src ids.
__global__ __launch_bounds__(256) void fill_kernel(
    const int* __restrict__ src, const int* __restrict__ dst,
    int* __restrict__ counts, int* __restrict__ eidx, int E) {
    int e = blockIdx.x * 256 + threadIdx.x;
    if (e >= E) return;
    int d = dst[e];
    int p = atomicAdd(&counts[d], 1);
    if (p < CAP) eidx[d * CAP + p] = src[e];
}

// x fp32 -> bf16 streaming cast (51MB working set -> L3-resident gather).
__global__ __launch_bounds__(256) void xcast_kernel(
    const float* __restrict__ x, unsigned short* __restrict__ xb, long n) {
    long i = ((long)blockIdx.x * 256 + threadIdx.x) * 8;
    if (i + 8 <= n) {
        float4 u0 = *(const float4*)(x + i);
        float4 u1 = *(const float4*)(x + i + 4);
        short8 o;
        o[0] = (short)f2bf(u0.x); o[1] = (short)f2bf(u0.y);
        o[2] = (short)f2bf(u0.z); o[3] = (short)f2bf(u0.w);
        o[4] = (short)f2bf(u1.x); o[5] = (short)f2bf(u1.y);
        o[6] = (short)f2bf(u1.z); o[7] = (short)f2bf(u1.w);
        *(short8*)(xb + i) = o;
    } else {
        for (; i < n; ++i) xb[i] = f2bf(x[i]);
    }
}

// One wave per constraint row; batch-8 keeps 8 row-loads in flight.
// Emits pre-scaled bf16 agg [num_con][256].
__global__ __launch_bounds__(256) void gather_kernel(
    const unsigned short* __restrict__ xb, const int* __restrict__ counts,
    const int* __restrict__ eidx, unsigned short* __restrict__ agg,
    int num_con) {
    int row  = blockIdx.x * 4 + (threadIdx.x >> 6);
    int lane = threadIdx.x & 63;
    if (row >= num_con) return;
    int cnt = counts[row];
    int cgo = min(cnt, CAP);
    int sid = (lane < cgo) ? eidx[row * CAP + lane] : 0;
    float a0 = 0.f, a1 = 0.f, a2 = 0.f, a3 = 0.f;
#pragma unroll 1
    for (int i = 0; i < cgo; i += 8) {
        int s[8];
#pragma unroll
        for (int u = 0; u < 8; ++u) s[u] = __shfl(sid, i + u, 64);
        s16x4 v[8];
#pragma unroll
        for (int u = 0; u < 8; ++u)
            v[u] = *(const s16x4*)(xb + (long)s[u] * HD + lane * 4);
#pragma unroll
        for (int u = 0; u < 8; ++u) {
            float wg = (i + u < cgo) ? 1.f : 0.f;
            a0 = fmaf(bf2f((unsigned short)v[u][0]), wg, a0);
            a1 = fmaf(bf2f((unsigned short)v[u][1]), wg, a1);
            a2 = fmaf(bf2f((unsigned short)v[u][2]), wg, a2);
            a3 = fmaf(bf2f((unsigned short)v[u][3]), wg, a3);
        }
    }
    float sc = 1.0f / ((float)cnt + DEG_EPS);
    s16x4 o;
    o[0] = (short)f2bf(a0 * sc); o[1] = (short)f2bf(a1 * sc);
    o[2] = (short)f2bf(a2 * sc); o[3] = (short)f2bf(a3 * sc);
    *(s16x4*)(agg + (long)row * HD + lane * 4) = o;
}

// GEMM1, weight-stationary, 64-row tile per block (4 rowtiles, prefetch).
// 256 thr = 4 waves; wave w = 64-col strip of W1 (128 VGPR). One barrier.
// Epilogue packs bf16 col-pairs via shfl_xor -> u32 LDS writes (no 2B
// same-dword bank splits). M overwrites agg in place (block-local rows).
__global__ __launch_bounds__(256) void g1_kernel(
    unsigned short* __restrict__ agg, const int* __restrict__ counts,
    const unsigned short* __restrict__ w1b, const float* __restrict__ msg_b,
    int num_con) {

    __shared__ unsigned short sT[64 * C1];
    const int tid = threadIdx.x, w = tid >> 6, lane = tid & 63;
    const int lr = lane & 15, lg = lane >> 4;
    const int jb = w * 64;
    const int r0 = blockIdx.x * 64;

    short8 b1r[4][8];
#pragma unroll
    for (int jt = 0; jt < 4; ++jt)
#pragma unroll
        for (int ks = 0; ks < 8; ++ks)
            b1r[jt][ks] = *(const short8*)(w1b + (jb + jt * 16 + lr) * HD + lg * 8 + ks * 32);
    float bj[4];
#pragma unroll
    for (int jt = 0; jt < 4; ++jt) bj[jt] = msg_b[jb + jt * 16 + lr];

    short8 af[8];
    {
        int arc = min(r0 + lr, num_con - 1);
        const unsigned short* ap = agg + (long)arc * HD + lg * 8;
#pragma unroll
        for (int ks = 0; ks < 8; ++ks) af[ks] = *(const short8*)(ap + ks * 32);
    }
#pragma unroll 1
    for (int rr = 0; rr < 4; ++rr) {
        short8 afn[8];
        if (rr < 3) {
            int arc = min(r0 + (rr + 1) * 16 + lr, num_con - 1);
            const unsigned short* ap = agg + (long)arc * HD + lg * 8;
#pragma unroll
            for (int ks = 0; ks < 8; ++ks) afn[ks] = *(const short8*)(ap + ks * 32);
        }
        f32x4 acc[4] = {{0.f,0.f,0.f,0.f},{0.f,0.f,0.f,0.f},{0.f,0.f,0.f,0.f},{0.f,0.f,0.f,0.f}};
#pragma unroll
        for (int ks = 0; ks < 8; ++ks)
#pragma unroll
            for (int jt = 0; jt < 4; ++jt)
                acc[jt] = __builtin_amdgcn_mfma_f32_16x16x32_bf16(af[ks], b1r[jt][ks], acc[jt], 0, 0, 0);

        float trow[4];
#pragma unroll
        for (int q = 0; q < 4; ++q) {
            int rrw = r0 + rr * 16 + lg * 4 + q;
            float dvq = (rrw < num_con) ? (float)counts[rrw] : 0.f;
            trow[q] = dvq / (dvq + DEG_EPS);
        }
#pragma unroll
        for (int jt = 0; jt < 4; ++jt)
#pragma unroll
            for (int q = 0; q < 4; ++q) {
                float m = acc[jt][q] + trow[q] * bj[jt];
                unsigned short mb = f2bf(m);
                int nb = __shfl_xor((int)(unsigned int)mb, 1, 64);
                if (!(lr & 1)) {
                    unsigned int pk = (unsigned int)mb | (((unsigned int)nb & 0xFFFFu) << 16);
                    int rowt = rr * 16 + lg * 4 + q;
                    *(unsigned int*)((char*)sT + rowt * (C1 * 2) + (jb + jt * 16 + lr) * 2) = pk;
                }
            }
#pragma unroll
        for (int ks = 0; ks < 8; ++ks) af[ks] = afn[ks];
    }
    __syncthreads();
#pragma unroll
    for (int p = 0; p < 8; ++p) {
        int idx = tid + p * 256;
        int row = idx >> 5, seg = idx & 31;
        int grow = r0 + row;
        if (grow < num_con) {
            short8 v = *(const short8*)(&sT[row * C1 + seg * 8]);
            *(short8*)(agg + (long)grow * HD + seg * 8) = v;
        }
    }
}

// GEMM2, weight-stationary, 64-row tile; + clue col + bias + ReLU;
// z parked bf16 in LDS; one barrier; LN (8 thr/row, shfl_xor 1/2/4) +
// fully coalesced fp32 stores.
__global__ __launch_bounds__(256) void g2_kernel(
    const unsigned short* __restrict__ M, const float* __restrict__ clue,
    const unsigned short* __restrict__ w2b, const float* __restrict__ ucol,
    const float* __restrict__ upd_b,
    const float* __restrict__ ln_w, const float* __restrict__ ln_b,
    float* __restrict__ out, int num_con) {

    __shared__ unsigned short sZ[64 * C1];
    const int tid = threadIdx.x, w = tid >> 6, lane = tid & 63;
    const int lr = lane & 15, lg = lane >> 4;
    const int jb = w * 64;
    const int r0 = blockIdx.x * 64;

    short8 b2r[4][8];
#pragma unroll
    for (int jt = 0; jt < 4; ++jt)
#pragma unroll
        for (int ks = 0; ks < 8; ++ks)
            b2r[jt][ks] = *(const short8*)(w2b + (jb + jt * 16 + lr) * HD + lg * 8 + ks * 32);
    float uc[4], ub[4];
#pragma unroll
    for (int jt = 0; jt < 4; ++jt) {
        uc[jt] = ucol[jb + jt * 16 + lr];
        ub[jt] = upd_b[jb + jt * 16 + lr];
    }

    short8 af[8];
    {
        int arc = min(r0 + lr, num_con - 1);
        const unsigned short* ap = M + (long)arc * HD + lg * 8;
#pragma unroll
        for (int ks = 0; ks < 8; ++ks) af[ks] = *(const short8*)(ap + ks * 32);
    }
#pragma unroll 1
    for (int rr = 0; rr < 4; ++rr) {
        short8 afn[8];
        if (rr < 3) {
            int arc = min(r0 + (rr + 1) * 16 + lr, num_con - 1);
            const unsigned short* ap = M + (long)arc * HD + lg * 8;
#pragma unroll
            for (int ks = 0; ks < 8; ++ks) afn[ks] = *(const short8*)(ap + ks * 32);
        }
        f32x4 acc[4] = {{0.f,0.f,0.f,0.f},{0.f,0.f,0.f,0.f},{0.f,0.f,0.f,0.f},{0.f,0.f,0.f,0.f}};
#pragma unroll
        for (int ks = 0; ks < 8; ++ks)
#pragma unroll
            for (int jt = 0; jt < 4; ++jt)
                acc[jt] = __builtin_amdgcn_mfma_f32_16x16x32_bf16(af[ks], b2r[jt][ks], acc[jt], 0, 0, 0);

        float cl[4];
#pragma unroll
        for (int q = 0; q < 4; ++q)
            cl[q] = clue[min(r0 + rr * 16 + lg * 4 + q, num_con - 1)];
#pragma unroll
        for (int jt = 0; jt < 4; ++jt)
#pragma unroll
            for (int q = 0; q < 4; ++q) {
                float z = fmaxf(acc[jt][q] + uc[jt] * cl[q] + ub[jt], 0.0f);
                unsigned short zb = f2bf(z);
                int nb = __shfl_xor((int)(unsigned int)zb, 1, 64);
                if (!(lr & 1)) {
                    unsigned int pk = (unsigned int)zb | (((unsigned int)nb & 0xFFFFu) << 16);
                    int rowt = rr * 16 + lg * 4 + q;
                    *(unsigned int*)((char*)sZ + rowt * (C1 * 2) + (jb + jt * 16 + lr) * 2) = pk;
                }
            }
#pragma unroll
        for (int ks = 0; ks < 8; ++ks) af[ks] = afn[ks];
    }
    __syncthreads();

    // LN: 8 threads per row, 32 cols each; reduce with shfl_xor 1/2/4.
#pragma unroll 1
    for (int p = 0; p < 2; ++p) {
        int row = p * 32 + (tid >> 3);
        int cb = (tid & 7) * 32;
        const unsigned short* zp = &sZ[row * C1 + cb];
        float zv[32];
        float s = 0.f, s2 = 0.f;
#pragma unroll
        for (int k = 0; k < 4; ++k) {
            short8 v = *(const short8*)(zp + k * 8);
#pragma unroll
            for (int e = 0; e < 8; ++e) {
                float f = bf2f((unsigned short)v[e]);
                zv[k * 8 + e] = f;
                s += f; s2 += f * f;
            }
        }
        s  += __shfl_xor(s, 1, 64);  s  += __shfl_xor(s, 2, 64);  s  += __shfl_xor(s, 4, 64);
        s2 += __shfl_xor(s2, 1, 64); s2 += __shfl_xor(s2, 2, 64); s2 += __shfl_xor(s2, 4, 64);
        float mu = s * (1.0f / HD);
        float var = s2 * (1.0f / HD) - mu * mu;
        float rs = rsqrtf(var + LN_EPS);
        int grow = r0 + row;
        if (grow < num_con) {
            float* gp = out + (long)grow * HD + cb;
#pragma unroll
            for (int k = 0; k < 8; ++k) {
                f32x4 lw = *(const f32x4*)(ln_w + cb + k * 4);
                f32x4 lb = *(const f32x4*)(ln_b + cb + k * 4);
                f32x4 o;
#pragma unroll
                for (int e = 0; e < 4; ++e)
                    o[e] = (zv[k * 4 + e] - mu) * rs * lw[e] + lb[e];
                *(f32x4*)(gp + k * 4) = o;
            }
        }
    }
}

extern "C" void kernel_launch(void* const* d_in, const int* in_sizes, int n_in,
                              void* d_out, int out_size, void* d_ws, size_t ws_size,
                              hipStream_t stream) {
    const float* x_var = (const float*)d_in[0];
    const int*   src   = (const int*)d_in[1];
    const int*   dst   = (const int*)d_in[2];
    const float* clue  = (const float*)d_in[3];
    // d_in[4] = num_con scalar (derived from out_size instead)
    const float* msg_W = (const float*)d_in[5];
    const float* msg_b = (const float*)d_in[6];
    const float* upd_W = (const float*)d_in[7];
    const float* upd_b = (const float*)d_in[8];
    const float* ln_w  = (const float*)d_in[9];
    const float* ln_b  = (const float*)d_in[10];

    int E = in_sizes[1];
    long n_x = in_sizes[0];
    int n_var = (int)(n_x / HD);
    int num_con = out_size / HD;
    int nblk = (num_con + 63) / 64;

    char* ws = (char*)d_ws;
    int* counts = (int*)ws;                               // num_con ints
    int* eidx   = (int*)(ws + (((size_t)num_con * 4 + 255) & ~(size_t)255));
    char* after = (char*)(eidx + (size_t)num_con * CAP);  // num_con*CAP ints
    size_t xoff = ((size_t)(after - ws) + 255) & ~(size_t)255;
    unsigned short* xb = (unsigned short*)(ws + xoff);    // n_var*256 bf16
    size_t aoff = (xoff + (size_t)n_var * HD * 2 + 255) & ~(size_t)255;
    unsigned short* agg = (unsigned short*)(ws + aoff);   // num_con*256 bf16 (then M)
    size_t woff = (aoff + (size_t)num_con * HD * 2 + 255) & ~(size_t)255;
    unsigned short* w1b = (unsigned short*)(ws + woff);
    unsigned short* w2b = w1b + 256 * 256;
    float* ucol = (float*)(w2b + 256 * 256);

    (void)hipMemsetAsync(counts, 0, (size_t)num_con * 4, stream);

    prep_kernel<<<256, 256, 0, stream>>>(msg_W, upd_W, w1b, w2b, ucol);

    fill_kernel<<<(E + 255) / 256, 256, 0, stream>>>(src, dst, counts, eidx, E);

    xcast_kernel<<<(int)((n_x / 8 + 255) / 256), 256, 0, stream>>>(x_var, xb, n_x);

    gather_kernel<<<(num_con + 3) / 4, 256, 0, stream>>>(
        xb, counts, eidx, agg, num_con);

    g1_kernel<<<nblk, 256, 0, stream>>>(agg, counts, w1b, msg_b, num_con);

    g2_kernel<<<nblk, 256, 0, stream>>>(agg, clue, w2b, ucol, upd_b, ln_w, ln_b,
                                        (float*)d_out, num_con);
}

// Round 11
// 132.137 us; speedup vs baseline: 1.3993x; 1.3993x over previous
//
#include <hip/hip_runtime.h>

#define HD 256
#define LN_EPS 1e-5f
#define DEG_EPS 1e-6f
#define CAP 64
#define C2 264

typedef __attribute__((ext_vector_type(8))) short short8;
typedef __attribute__((ext_vector_type(4))) short s16x4;
typedef __attribute__((ext_vector_type(4))) float f32x4;

__device__ inline unsigned short f2bf(float f) {
    union { float f; unsigned int u; } v; v.f = f;
    unsigned int r = v.u + 0x7FFFu + ((v.u >> 16) & 1u);
    return (unsigned short)(r >> 16);
}
__device__ inline float bf2f(unsigned short h) {
    union { unsigned int u; float f; } v; v.u = ((unsigned int)h) << 16;
    return v.f;
}

// W12 = W2[:, :256] @ W1 (fp32 accumulate -> bf16), bv = W2 @ b1,
// ucol[j] = W2[j][256]. Block j (256 blocks), thread k: coalesced over k.
__global__ __launch_bounds__(256) void w12_kernel(
    const float* __restrict__ msg_W, const float* __restrict__ msg_b,
    const float* __restrict__ upd_W,
    unsigned short* __restrict__ w12b, float* __restrict__ bv,
    float* __restrict__ ucol) {
    int j = blockIdx.x, k = threadIdx.x;
    float acc = 0.f, accb = 0.f;
#pragma unroll 4
    for (int m = 0; m < 256; ++m) {
        float w2 = upd_W[j * 257 + m];          // uniform (scalar) load
        acc  = fmaf(w2, msg_W[m * 256 + k], acc);   // coalesced over k
        accb = fmaf(w2, msg_b[m], accb);
    }
    w12b[j * 256 + k] = f2bf(acc);
    if (k == 0) { bv[j] = accb; ucol[j] = upd_W[j * 257 + 256]; }
}

// Bucket edges by dst: counts[] = degree, eidx[d*CAP + p] = src ids.
__global__ __launch_bounds__(256) void fill_kernel(
    const int* __restrict__ src, const int* __restrict__ dst,
    int* __restrict__ counts, int* __restrict__ eidx, int E) {
    int e = blockIdx.x * 256 + threadIdx.x;
    if (e >= E) return;
    int d = dst[e];
    int p = atomicAdd(&counts[d], 1);
    if (p < CAP) eidx[d * CAP + p] = src[e];
}

// x fp32 -> bf16 streaming cast (makes gather working set 51MB, L3-resident).
__global__ __launch_bounds__(256) void xcast_kernel(
    const float* __restrict__ x, unsigned short* __restrict__ xb, long n) {
    long i = ((long)blockIdx.x * 256 + threadIdx.x) * 8;
    if (i + 8 <= n) {
        float4 u0 = *(const float4*)(x + i);
        float4 u1 = *(const float4*)(x + i + 4);
        short8 o;
        o[0] = (short)f2bf(u0.x); o[1] = (short)f2bf(u0.y);
        o[2] = (short)f2bf(u0.z); o[3] = (short)f2bf(u0.w);
        o[4] = (short)f2bf(u1.x); o[5] = (short)f2bf(u1.y);
        o[6] = (short)f2bf(u1.z); o[7] = (short)f2bf(u1.w);
        *(short8*)(xb + i) = o;
    } else {
        for (; i < n; ++i) xb[i] = f2bf(x[i]);
    }
}

// One wave per constraint row; batch-8 keeps 8 row-loads in flight.
// Emits pre-scaled bf16 agg [num_con][256].
__global__ __launch_bounds__(256) void gather_kernel(
    const unsigned short* __restrict__ xb, const int* __restrict__ counts,
    const int* __restrict__ eidx, unsigned short* __restrict__ agg,
    int num_con) {
    int row  = blockIdx.x * 4 + (threadIdx.x >> 6);
    int lane = threadIdx.x & 63;
    if (row >= num_con) return;
    int cnt = counts[row];
    int cgo = min(cnt, CAP);
    int sid = (lane < cgo) ? eidx[row * CAP + lane] : 0;
    float a0 = 0.f, a1 = 0.f, a2 = 0.f, a3 = 0.f;
#pragma unroll 1
    for (int i = 0; i < cgo; i += 8) {
        int s[8];
#pragma unroll
        for (int u = 0; u < 8; ++u) s[u] = __shfl(sid, i + u, 64);
        s16x4 v[8];
#pragma unroll
        for (int u = 0; u < 8; ++u)
            v[u] = *(const s16x4*)(xb + (long)s[u] * HD + lane * 4);
#pragma unroll
        for (int u = 0; u < 8; ++u) {
            float wg = (i + u < cgo) ? 1.f : 0.f;
            a0 = fmaf(bf2f((unsigned short)v[u][0]), wg, a0);
            a1 = fmaf(bf2f((unsigned short)v[u][1]), wg, a1);
            a2 = fmaf(bf2f((unsigned short)v[u][2]), wg, a2);
            a3 = fmaf(bf2f((unsigned short)v[u][3]), wg, a3);
        }
    }
    float sc = 1.0f / ((float)cnt + DEG_EPS);
    s16x4 o;
    o[0] = (short)f2bf(a0 * sc); o[1] = (short)f2bf(a1 * sc);
    o[2] = (short)f2bf(a2 * sc); o[3] = (short)f2bf(a3 * sc);
    *(s16x4*)(agg + (long)row * HD + lane * 4) = o;
}

// Single fused GEMM (R7-g2 structure + tcoef*bv term):
// out = LN(relu(agg @ W12^T + tcoef*bv + ucol*clue + b2)) * ln_w + ln_b.
// 256 thr = 4 waves; wave w holds W12 rows [w*64, w*64+64) in 128 VGPR
// (weight-stationary, loaded once). Grid-stride over 16-row tiles;
// z fp32 in double-buffered LDS; LN 16 thr/row via shfl_xor; coalesced.
__global__ __launch_bounds__(256) void gfinal_kernel(
    const unsigned short* __restrict__ agg, const int* __restrict__ counts,
    const float* __restrict__ clue,
    const unsigned short* __restrict__ w12b, const float* __restrict__ bv,
    const float* __restrict__ ucol, const float* __restrict__ upd_b,
    const float* __restrict__ ln_w, const float* __restrict__ ln_b,
    float* __restrict__ out, int num_con, int ntiles) {

    __shared__ float sZ[2][16 * C2];
    const int tid = threadIdx.x, w = tid >> 6, lane = tid & 63;
    const int lr = lane & 15, lg = lane >> 4;

    short8 bfr[4][8];
#pragma unroll
    for (int jt = 0; jt < 4; ++jt)
#pragma unroll
        for (int ks = 0; ks < 8; ++ks)
            bfr[jt][ks] = *(const short8*)(w12b + (w * 64 + jt * 16 + lr) * HD + lg * 8 + ks * 32);
    float uc[4], b2[4], bvv[4];
#pragma unroll
    for (int jt = 0; jt < 4; ++jt) {
        uc[jt]  = ucol[w * 64 + jt * 16 + lr];
        b2[jt]  = upd_b[w * 64 + jt * 16 + lr];
        bvv[jt] = bv[w * 64 + jt * 16 + lr];
    }
    // per-thread LN params for cols seg*16..seg*16+15 (store phase)
    const int seg = tid & 15;
    f32x4 lw[4], lb[4];
#pragma unroll
    for (int k = 0; k < 4; ++k) {
        lw[k] = *(const f32x4*)(ln_w + seg * 16 + k * 4);
        lb[k] = *(const f32x4*)(ln_b + seg * 16 + k * 4);
    }

    int buf = 0;
#pragma unroll 1
    for (int rt = blockIdx.x; rt < ntiles; rt += gridDim.x) {
        int r0 = rt * 16;
        int arc = min(r0 + lr, num_con - 1);
        const unsigned short* ap = agg + (long)arc * HD + lg * 8;
        short8 af[8];
#pragma unroll
        for (int ks = 0; ks < 8; ++ks) af[ks] = *(const short8*)(ap + ks * 32);

        f32x4 acc[4] = {{0.f,0.f,0.f,0.f},{0.f,0.f,0.f,0.f},{0.f,0.f,0.f,0.f},{0.f,0.f,0.f,0.f}};
#pragma unroll
        for (int ks = 0; ks < 8; ++ks)
#pragma unroll
            for (int jt = 0; jt < 4; ++jt)
                acc[jt] = __builtin_amdgcn_mfma_f32_16x16x32_bf16(af[ks], bfr[jt][ks], acc[jt], 0, 0, 0);

        float cl[4], trow[4];
#pragma unroll
        for (int q = 0; q < 4; ++q) {
            int rr = min(r0 + lg * 4 + q, num_con - 1);
            cl[q] = clue[rr];
            float dvq = (float)counts[rr];
            trow[q] = dvq / (dvq + DEG_EPS);
        }
#pragma unroll
        for (int jt = 0; jt < 4; ++jt)
#pragma unroll
            for (int q = 0; q < 4; ++q) {
                float z = fmaxf(acc[jt][q] + trow[q] * bvv[jt] + uc[jt] * cl[q] + b2[jt], 0.0f);
                sZ[buf][(lg * 4 + q) * C2 + w * 64 + jt * 16 + lr] = z;
            }
        __syncthreads();
        {
            int row = tid >> 4;
            const float* zp = &sZ[buf][row * C2 + seg * 16];
            f32x4 z4[4];
            float s = 0.f, s2 = 0.f;
#pragma unroll
            for (int k = 0; k < 4; ++k) {
                z4[k] = *(const f32x4*)(zp + k * 4);
#pragma unroll
                for (int e = 0; e < 4; ++e) { s += z4[k][e]; s2 += z4[k][e] * z4[k][e]; }
            }
#pragma unroll
            for (int m = 1; m < 16; m <<= 1) {
                s  += __shfl_xor(s,  m, 64);
                s2 += __shfl_xor(s2, m, 64);
            }
            float mu = s * (1.0f / HD);
            float var = s2 * (1.0f / HD) - mu * mu;
            float rs = rsqrtf(var + LN_EPS);
            int grow = r0 + row;
            if (grow < num_con) {
                float* gp = out + (long)grow * HD + seg * 16;
#pragma unroll
                for (int k = 0; k < 4; ++k) {
                    f32x4 o;
#pragma unroll
                    for (int e = 0; e < 4; ++e)
                        o[e] = (z4[k][e] - mu) * rs * lw[k][e] + lb[k][e];
                    *(f32x4*)(gp + k * 4) = o;
                }
            }
        }
        buf ^= 1;
    }
}

extern "C" void kernel_launch(void* const* d_in, const int* in_sizes, int n_in,
                              void* d_out, int out_size, void* d_ws, size_t ws_size,
                              hipStream_t stream) {
    const float* x_var = (const float*)d_in[0];
    const int*   src   = (const int*)d_in[1];
    const int*   dst   = (const int*)d_in[2];
    const float* clue  = (const float*)d_in[3];
    // d_in[4] = num_con scalar (derived from out_size instead)
    const float* msg_W = (const float*)d_in[5];
    const float* msg_b = (const float*)d_in[6];
    const float* upd_W = (const float*)d_in[7];
    const float* upd_b = (const float*)d_in[8];
    const float* ln_w  = (const float*)d_in[9];
    const float* ln_b  = (const float*)d_in[10];

    int E = in_sizes[1];
    long n_x = in_sizes[0];
    int n_var = (int)(n_x / HD);
    int num_con = out_size / HD;
    int ntiles = (num_con + 15) / 16;

    char* ws = (char*)d_ws;
    int* counts = (int*)ws;                               // num_con ints
    int* eidx   = (int*)(ws + (((size_t)num_con * 4 + 255) & ~(size_t)255));
    char* after = (char*)(eidx + (size_t)num_con * CAP);  // num_con*CAP ints
    size_t xoff = ((size_t)(after - ws) + 255) & ~(size_t)255;
    unsigned short* xb = (unsigned short*)(ws + xoff);    // n_var*256 bf16
    size_t aoff = (xoff + (size_t)n_var * HD * 2 + 255) & ~(size_t)255;
    unsigned short* agg = (unsigned short*)(ws + aoff);   // num_con*256 bf16
    size_t woff = (aoff + (size_t)num_con * HD * 2 + 255) & ~(size_t)255;
    unsigned short* w12b = (unsigned short*)(ws + woff);  // 256*256 bf16
    float* bvp  = (float*)(w12b + 256 * 256);             // 256 fp32
    float* ucol = bvp + 256;                              // 256 fp32

    (void)hipMemsetAsync(counts, 0, (size_t)num_con * 4, stream);

    w12_kernel<<<256, 256, 0, stream>>>(msg_W, msg_b, upd_W, w12b, bvp, ucol);

    fill_kernel<<<(E + 255) / 256, 256, 0, stream>>>(src, dst, counts, eidx, E);

    xcast_kernel<<<(int)((n_x / 8 + 255) / 256), 256, 0, stream>>>(x_var, xb, n_x);

    gather_kernel<<<(num_con + 3) / 4, 256, 0, stream>>>(
        xb, counts, eidx, agg, num_con);

    gfinal_kernel<<<512, 256, 0, stream>>>(
        agg, counts, clue, w12b, bvp, ucol, upd_b, ln_w, ln_b,
        (float*)d_out, num_con, ntiles);
}

// Round 12
// 131.464 us; speedup vs baseline: 1.4064x; 1.0051x over previous
//
#include <hip/hip_runtime.h>

#define HD 256
#define LN_EPS 1e-5f
#define DEG_EPS 1e-6f
#define CAP 64
#define C2 264

typedef __attribute__((ext_vector_type(8))) short short8;
typedef __attribute__((ext_vector_type(4))) short s16x4;
typedef __attribute__((ext_vector_type(4))) float f32x4;
typedef __attribute__((ext_vector_type(4))) int i32x4;

__device__ inline unsigned short f2bf(float f) {
    union { float f; unsigned int u; } v; v.f = f;
    unsigned int r = v.u + 0x7FFFu + ((v.u >> 16) & 1u);
    return (unsigned short)(r >> 16);
}
__device__ inline float bf2f(unsigned short h) {
    union { unsigned int u; float f; } v; v.u = ((unsigned int)h) << 16;
    return v.f;
}

// Zero `counts` (n ints) — replaces hipMemsetAsync, whose runtime fill
// kernel costs ~60us fixed overhead in-graph on this chip (R11 profile).
__global__ __launch_bounds__(256) void zero_kernel(int* __restrict__ p, int n) {
    int i = (blockIdx.x * 256 + threadIdx.x) * 4;
    if (i + 4 <= n) {
        *(i32x4*)(p + i) = (i32x4){0, 0, 0, 0};
    } else {
        for (; i < n; ++i) p[i] = 0;
    }
}

// W12 = W2[:, :256] @ W1 (fp32 accumulate -> bf16), bv = W2 @ b1,
// ucol[j] = W2[j][256]. Block j (256 blocks), thread k: coalesced over k.
__global__ __launch_bounds__(256) void w12_kernel(
    const float* __restrict__ msg_W, const float* __restrict__ msg_b,
    const float* __restrict__ upd_W,
    unsigned short* __restrict__ w12b, float* __restrict__ bv,
    float* __restrict__ ucol) {
    int j = blockIdx.x, k = threadIdx.x;
    float acc = 0.f, accb = 0.f;
#pragma unroll 4
    for (int m = 0; m < 256; ++m) {
        float w2 = upd_W[j * 257 + m];          // uniform (scalar) load
        acc  = fmaf(w2, msg_W[m * 256 + k], acc);   // coalesced over k
        accb = fmaf(w2, msg_b[m], accb);
    }
    w12b[j * 256 + k] = f2bf(acc);
    if (k == 0) { bv[j] = accb; ucol[j] = upd_W[j * 257 + 256]; }
}

// Bucket edges by dst: counts[] = degree, eidx[d*CAP + p] = src ids.
__global__ __launch_bounds__(256) void fill_kernel(
    const int* __restrict__ src, const int* __restrict__ dst,
    int* __restrict__ counts, int* __restrict__ eidx, int E) {
    int e = blockIdx.x * 256 + threadIdx.x;
    if (e >= E) return;
    int d = dst[e];
    int p = atomicAdd(&counts[d], 1);
    if (p < CAP) eidx[d * CAP + p] = src[e];
}

// x fp32 -> bf16 streaming cast (makes gather working set 51MB, L3-resident).
__global__ __launch_bounds__(256) void xcast_kernel(
    const float* __restrict__ x, unsigned short* __restrict__ xb, long n) {
    long i = ((long)blockIdx.x * 256 + threadIdx.x) * 8;
    if (i + 8 <= n) {
        float4 u0 = *(const float4*)(x + i);
        float4 u1 = *(const float4*)(x + i + 4);
        short8 o;
        o[0] = (short)f2bf(u0.x); o[1] = (short)f2bf(u0.y);
        o[2] = (short)f2bf(u0.z); o[3] = (short)f2bf(u0.w);
        o[4] = (short)f2bf(u1.x); o[5] = (short)f2bf(u1.y);
        o[6] = (short)f2bf(u1.z); o[7] = (short)f2bf(u1.w);
        *(short8*)(xb + i) = o;
    } else {
        for (; i < n; ++i) xb[i] = f2bf(x[i]);
    }
}

// One wave per constraint row; batch-8 keeps 8 row-loads in flight.
// Emits pre-scaled bf16 agg [num_con][256].
__global__ __launch_bounds__(256) void gather_kernel(
    const unsigned short* __restrict__ xb, const int* __restrict__ counts,
    const int* __restrict__ eidx, unsigned short* __restrict__ agg,
    int num_con) {
    int row  = blockIdx.x * 4 + (threadIdx.x >> 6);
    int lane = threadIdx.x & 63;
    if (row >= num_con) return;
    int cnt = counts[row];
    int cgo = min(cnt, CAP);
    int sid = (lane < cgo) ? eidx[row * CAP + lane] : 0;
    float a0 = 0.f, a1 = 0.f, a2 = 0.f, a3 = 0.f;
#pragma unroll 1
    for (int i = 0; i < cgo; i += 8) {
        int s[8];
#pragma unroll
        for (int u = 0; u < 8; ++u) s[u] = __shfl(sid, i + u, 64);
        s16x4 v[8];
#pragma unroll
        for (int u = 0; u < 8; ++u)
            v[u] = *(const s16x4*)(xb + (long)s[u] * HD + lane * 4);
#pragma unroll
        for (int u = 0; u < 8; ++u) {
            float wg = (i + u < cgo) ? 1.f : 0.f;
            a0 = fmaf(bf2f((unsigned short)v[u][0]), wg, a0);
            a1 = fmaf(bf2f((unsigned short)v[u][1]), wg, a1);
            a2 = fmaf(bf2f((unsigned short)v[u][2]), wg, a2);
            a3 = fmaf(bf2f((unsigned short)v[u][3]), wg, a3);
        }
    }
    float sc = 1.0f / ((float)cnt + DEG_EPS);
    s16x4 o;
    o[0] = (short)f2bf(a0 * sc); o[1] = (short)f2bf(a1 * sc);
    o[2] = (short)f2bf(a2 * sc); o[3] = (short)f2bf(a3 * sc);
    *(s16x4*)(agg + (long)row * HD + lane * 4) = o;
}

// Single fused GEMM:
// out = LN(relu(agg @ W12^T + tcoef*bv + ucol*clue + b2)) * ln_w + ln_b.
// 256 thr = 4 waves; wave w holds W12 rows [w*64, w*64+64) in 128 VGPR
// (weight-stationary, loaded once). Grid-stride over 16-row tiles;
// z fp32 in double-buffered LDS; LN 16 thr/row via shfl_xor; coalesced.
__global__ __launch_bounds__(256) void gfinal_kernel(
    const unsigned short* __restrict__ agg, const int* __restrict__ counts,
    const float* __restrict__ clue,
    const unsigned short* __restrict__ w12b, const float* __restrict__ bv,
    const float* __restrict__ ucol, const float* __restrict__ upd_b,
    const float* __restrict__ ln_w, const float* __restrict__ ln_b,
    float* __restrict__ out, int num_con, int ntiles) {

    __shared__ float sZ[2][16 * C2];
    const int tid = threadIdx.x, w = tid >> 6, lane = tid & 63;
    const int lr = lane & 15, lg = lane >> 4;

    short8 bfr[4][8];
#pragma unroll
    for (int jt = 0; jt < 4; ++jt)
#pragma unroll
        for (int ks = 0; ks < 8; ++ks)
            bfr[jt][ks] = *(const short8*)(w12b + (w * 64 + jt * 16 + lr) * HD + lg * 8 + ks * 32);
    float uc[4], b2[4], bvv[4];
#pragma unroll
    for (int jt = 0; jt < 4; ++jt) {
        uc[jt]  = ucol[w * 64 + jt * 16 + lr];
        b2[jt]  = upd_b[w * 64 + jt * 16 + lr];
        bvv[jt] = bv[w * 64 + jt * 16 + lr];
    }
    // per-thread LN params for cols seg*16..seg*16+15 (store phase)
    const int seg = tid & 15;
    f32x4 lw[4], lb[4];
#pragma unroll
    for (int k = 0; k < 4; ++k) {
        lw[k] = *(const f32x4*)(ln_w + seg * 16 + k * 4);
        lb[k] = *(const f32x4*)(ln_b + seg * 16 + k * 4);
    }

    int buf = 0;
#pragma unroll 1
    for (int rt = blockIdx.x; rt < ntiles; rt += gridDim.x) {
        int r0 = rt * 16;
        int arc = min(r0 + lr, num_con - 1);
        const unsigned short* ap = agg + (long)arc * HD + lg * 8;
        short8 af[8];
#pragma unroll
        for (int ks = 0; ks < 8; ++ks) af[ks] = *(const short8*)(ap + ks * 32);

        f32x4 acc[4] = {{0.f,0.f,0.f,0.f},{0.f,0.f,0.f,0.f},{0.f,0.f,0.f,0.f},{0.f,0.f,0.f,0.f}};
#pragma unroll
        for (int ks = 0; ks < 8; ++ks)
#pragma unroll
            for (int jt = 0; jt < 4; ++jt)
                acc[jt] = __builtin_amdgcn_mfma_f32_16x16x32_bf16(af[ks], bfr[jt][ks], acc[jt], 0, 0, 0);

        float cl[4], trow[4];
#pragma unroll
        for (int q = 0; q < 4; ++q) {
            int rr = min(r0 + lg * 4 + q, num_con - 1);
            cl[q] = clue[rr];
            float dvq = (float)counts[rr];
            trow[q] = dvq / (dvq + DEG_EPS);
        }
#pragma unroll
        for (int jt = 0; jt < 4; ++jt)
#pragma unroll
            for (int q = 0; q < 4; ++q) {
                float z = fmaxf(acc[jt][q] + trow[q] * bvv[jt] + uc[jt] * cl[q] + b2[jt], 0.0f);
                sZ[buf][(lg * 4 + q) * C2 + w * 64 + jt * 16 + lr] = z;
            }
        __syncthreads();
        {
            int row = tid >> 4;
            const float* zp = &sZ[buf][row * C2 + seg * 16];
            f32x4 z4[4];
            float s = 0.f, s2 = 0.f;
#pragma unroll
            for (int k = 0; k < 4; ++k) {
                z4[k] = *(const f32x4*)(zp + k * 4);
#pragma unroll
                for (int e = 0; e < 4; ++e) { s += z4[k][e]; s2 += z4[k][e] * z4[k][e]; }
            }
#pragma unroll
            for (int m = 1; m < 16; m <<= 1) {
                s  += __shfl_xor(s,  m, 64);
                s2 += __shfl_xor(s2, m, 64);
            }
            float mu = s * (1.0f / HD);
            float var = s2 * (1.0f / HD) - mu * mu;
            float rs = rsqrtf(var + LN_EPS);
            int grow = r0 + row;
            if (grow < num_con) {
                float* gp = out + (long)grow * HD + seg * 16;
#pragma unroll
                for (int k = 0; k < 4; ++k) {
                    f32x4 o;
#pragma unroll
                    for (int e = 0; e < 4; ++e)
                        o[e] = (z4[k][e] - mu) * rs * lw[k][e] + lb[k][e];
                    *(f32x4*)(gp + k * 4) = o;
                }
            }
        }
        buf ^= 1;
    }
}

extern "C" void kernel_launch(void* const* d_in, const int* in_sizes, int n_in,
                              void* d_out, int out_size, void* d_ws, size_t ws_size,
                              hipStream_t stream) {
    const float* x_var = (const float*)d_in[0];
    const int*   src   = (const int*)d_in[1];
    const int*   dst   = (const int*)d_in[2];
    const float* clue  = (const float*)d_in[3];
    // d_in[4] = num_con scalar (derived from out_size instead)
    const float* msg_W = (const float*)d_in[5];
    const float* msg_b = (const float*)d_in[6];
    const float* upd_W = (const float*)d_in[7];
    const float* upd_b = (const float*)d_in[8];
    const float* ln_w  = (const float*)d_in[9];
    const float* ln_b  = (const float*)d_in[10];

    int E = in_sizes[1];
    long n_x = in_sizes[0];
    int n_var = (int)(n_x / HD);
    int num_con = out_size / HD;
    int ntiles = (num_con + 15) / 16;

    char* ws = (char*)d_ws;
    int* counts = (int*)ws;                               // num_con ints
    int* eidx   = (int*)(ws + (((size_t)num_con * 4 + 255) & ~(size_t)255));
    char* after = (char*)(eidx + (size_t)num_con * CAP);  // num_con*CAP ints
    size_t xoff = ((size_t)(after - ws) + 255) & ~(size_t)255;
    unsigned short* xb = (unsigned short*)(ws + xoff);    // n_var*256 bf16
    size_t aoff = (xoff + (size_t)n_var * HD * 2 + 255) & ~(size_t)255;
    unsigned short* agg = (unsigned short*)(ws + aoff);   // num_con*256 bf16
    size_t woff = (aoff + (size_t)num_con * HD * 2 + 255) & ~(size_t)255;
    unsigned short* w12b = (unsigned short*)(ws + woff);  // 256*256 bf16
    float* bvp  = (float*)(w12b + 256 * 256);             // 256 fp32
    float* ucol = bvp + 256;                              // 256 fp32

    zero_kernel<<<(num_con + 1023) / 1024, 256, 0, stream>>>(counts, num_con);

    w12_kernel<<<256, 256, 0, stream>>>(msg_W, msg_b, upd_W, w12b, bvp, ucol);

    fill_kernel<<<(E + 255) / 256, 256, 0, stream>>>(src, dst, counts, eidx, E);

    xcast_kernel<<<(int)((n_x / 8 + 255) / 256), 256, 0, stream>>>(x_var, xb, n_x);

    gather_kernel<<<(num_con + 3) / 4, 256, 0, stream>>>(
        xb, counts, eidx, agg, num_con);

    gfinal_kernel<<<512, 256, 0, stream>>>(
        agg, counts, clue, w12b, bvp, ucol, upd_b, ln_w, ln_b,
        (float*)d_out, num_con, ntiles);
}

// Round 13
// 123.748 us; speedup vs baseline: 1.4941x; 1.0624x over previous
//
#include <hip/hip_runtime.h>

#define HD 256
#define LN_EPS 1e-5f
#define DEG_EPS 1e-6f
#define CAP 64
#define C2 264

typedef __attribute__((ext_vector_type(8))) short short8;
typedef __attribute__((ext_vector_type(4))) short s16x4;
typedef __attribute__((ext_vector_type(4))) float f32x4;
typedef __attribute__((ext_vector_type(4))) int i32x4;

__device__ inline unsigned short f2bf(float f) {
    union { float f; unsigned int u; } v; v.f = f;
    unsigned int r = v.u + 0x7FFFu + ((v.u >> 16) & 1u);
    return (unsigned short)(r >> 16);
}
__device__ inline float bf2f(unsigned short h) {
    union { unsigned int u; float f; } v; v.u = ((unsigned int)h) << 16;
    return v.f;
}

// Merged prep: blocks [0,zb) zero counts; [zb,zb+256) W12=W2@W1 (+bv,ucol);
// [zb+256, ...) x fp32->bf16 cast. All independent; zero/w12 hide under
// the xcast BW time, and 2 launch gaps are saved.
__global__ __launch_bounds__(256) void prep_kernel(
    int* __restrict__ counts, int num_con,
    const float* __restrict__ msg_W, const float* __restrict__ msg_b,
    const float* __restrict__ upd_W,
    unsigned short* __restrict__ w12b, float* __restrict__ bv,
    float* __restrict__ ucol,
    const float* __restrict__ x, unsigned short* __restrict__ xb, long n,
    int zb) {
    int b = blockIdx.x, tid = threadIdx.x;
    if (b < zb) {
        int i = (b * 256 + tid) * 4;
        if (i + 4 <= num_con) *(i32x4*)(counts + i) = (i32x4){0, 0, 0, 0};
        else for (; i < num_con; ++i) counts[i] = 0;
    } else if (b < zb + 256) {
        int j = b - zb, k = tid;
        float acc = 0.f, accb = 0.f;
#pragma unroll 4
        for (int m = 0; m < 256; ++m) {
            float w2 = upd_W[j * 257 + m];              // uniform load
            acc  = fmaf(w2, msg_W[m * 256 + k], acc);   // coalesced over k
            accb = fmaf(w2, msg_b[m], accb);
        }
        w12b[j * 256 + k] = f2bf(acc);
        if (k == 0) { bv[j] = accb; ucol[j] = upd_W[j * 257 + 256]; }
    } else {
        long i = ((long)(b - zb - 256) * 256 + tid) * 8;
        if (i + 8 <= n) {
            float4 u0 = *(const float4*)(x + i);
            float4 u1 = *(const float4*)(x + i + 4);
            short8 o;
            o[0] = (short)f2bf(u0.x); o[1] = (short)f2bf(u0.y);
            o[2] = (short)f2bf(u0.z); o[3] = (short)f2bf(u0.w);
            o[4] = (short)f2bf(u1.x); o[5] = (short)f2bf(u1.y);
            o[6] = (short)f2bf(u1.z); o[7] = (short)f2bf(u1.w);
            *(short8*)(xb + i) = o;
        } else {
            for (; i < n; ++i) xb[i] = f2bf(x[i]);
        }
    }
}

// Bucket edges by dst: counts[] = degree, eidx[d*CAP + p] = src ids.
__global__ __launch_bounds__(256) void fill_kernel(
    const int* __restrict__ src, const int* __restrict__ dst,
    int* __restrict__ counts, int* __restrict__ eidx, int E) {
    int e = blockIdx.x * 256 + threadIdx.x;
    if (e >= E) return;
    int d = dst[e];
    int p = atomicAdd(&counts[d], 1);
    if (p < CAP) eidx[d * CAP + p] = src[e];
}

// One wave per constraint row; batch-8 keeps 8 row-loads in flight.
// Emits pre-scaled bf16 agg [num_con][256].
__global__ __launch_bounds__(256) void gather_kernel(
    const unsigned short* __restrict__ xb, const int* __restrict__ counts,
    const int* __restrict__ eidx, unsigned short* __restrict__ agg,
    int num_con) {
    int row  = blockIdx.x * 4 + (threadIdx.x >> 6);
    int lane = threadIdx.x & 63;
    if (row >= num_con) return;
    int cnt = counts[row];
    int cgo = min(cnt, CAP);
    int sid = (lane < cgo) ? eidx[row * CAP + lane] : 0;
    float a0 = 0.f, a1 = 0.f, a2 = 0.f, a3 = 0.f;
#pragma unroll 1
    for (int i = 0; i < cgo; i += 8) {
        int s[8];
#pragma unroll
        for (int u = 0; u < 8; ++u) s[u] = __shfl(sid, i + u, 64);
        s16x4 v[8];
#pragma unroll
        for (int u = 0; u < 8; ++u)
            v[u] = *(const s16x4*)(xb + (long)s[u] * HD + lane * 4);
#pragma unroll
        for (int u = 0; u < 8; ++u) {
            float wg = (i + u < cgo) ? 1.f : 0.f;
            a0 = fmaf(bf2f((unsigned short)v[u][0]), wg, a0);
            a1 = fmaf(bf2f((unsigned short)v[u][1]), wg, a1);
            a2 = fmaf(bf2f((unsigned short)v[u][2]), wg, a2);
            a3 = fmaf(bf2f((unsigned short)v[u][3]), wg, a3);
        }
    }
    float sc = 1.0f / ((float)cnt + DEG_EPS);
    s16x4 o;
    o[0] = (short)f2bf(a0 * sc); o[1] = (short)f2bf(a1 * sc);
    o[2] = (short)f2bf(a2 * sc); o[3] = (short)f2bf(a3 * sc);
    *(s16x4*)(agg + (long)row * HD + lane * 4) = o;
}

// Single fused GEMM:
// out = LN(relu(agg @ W12^T + tcoef*bv + ucol*clue + b2)) * ln_w + ln_b.
// 4 waves; wave w holds W12 rows [w*64,+64) in 128 VGPR. A-tile staged
// cooperatively in XOR-swizzled LDS ONCE per tile (was 4x redundant
// global reads, one per wave). Grid-stride over 16-row tiles.
__global__ __launch_bounds__(256) void gfinal_kernel(
    const unsigned short* __restrict__ agg, const int* __restrict__ counts,
    const float* __restrict__ clue,
    const unsigned short* __restrict__ w12b, const float* __restrict__ bv,
    const float* __restrict__ ucol, const float* __restrict__ upd_b,
    const float* __restrict__ ln_w, const float* __restrict__ ln_b,
    float* __restrict__ out, int num_con, int ntiles) {

    __shared__ unsigned short sA[16 * 256];   // 8 KB, XOR-swizzled rows
    __shared__ float sZ[2][16 * C2];
    const int tid = threadIdx.x, w = tid >> 6, lane = tid & 63;
    const int lr = lane & 15, lg = lane >> 4;

    short8 bfr[4][8];
#pragma unroll
    for (int jt = 0; jt < 4; ++jt)
#pragma unroll
        for (int ks = 0; ks < 8; ++ks)
            bfr[jt][ks] = *(const short8*)(w12b + (w * 64 + jt * 16 + lr) * HD + lg * 8 + ks * 32);
    float uc[4], b2[4], bvv[4];
#pragma unroll
    for (int jt = 0; jt < 4; ++jt) {
        uc[jt]  = ucol[w * 64 + jt * 16 + lr];
        b2[jt]  = upd_b[w * 64 + jt * 16 + lr];
        bvv[jt] = bv[w * 64 + jt * 16 + lr];
    }
    // per-thread LN params for cols seg*16..seg*16+15 (store phase)
    const int seg = tid & 15;
    f32x4 lw[4], lb[4];
#pragma unroll
    for (int k = 0; k < 4; ++k) {
        lw[k] = *(const f32x4*)(ln_w + seg * 16 + k * 4);
        lb[k] = *(const f32x4*)(ln_b + seg * 16 + k * 4);
    }
    // staging indices: 16 threads/row, 32B (2x16B) per thread
    const int srow = tid >> 4, scol = (tid & 15) * 16;   // col in shorts

    int buf = 0;
#pragma unroll 1
    for (int rt = blockIdx.x; rt < ntiles; rt += gridDim.x) {
        int r0 = rt * 16;
        // ---- cooperative A-tile stage (once, was 4x) ----
        {
            int arc = min(r0 + srow, num_con - 1);
            const unsigned short* gp = agg + (long)arc * HD + scol;
            short8 v0 = *(const short8*)(gp);
            short8 v1 = *(const short8*)(gp + 8);
            int b0 = (srow * 512 + scol * 2) ^ ((srow & 7) << 4);
            int b1 = (srow * 512 + scol * 2 + 16) ^ ((srow & 7) << 4);
            *(short8*)((char*)sA + b0) = v0;
            *(short8*)((char*)sA + b1) = v1;
        }
        __syncthreads();

        short8 af[8];
#pragma unroll
        for (int ks = 0; ks < 8; ++ks) {
            int byte = (lr * 512 + (ks * 32 + lg * 8) * 2) ^ ((lr & 7) << 4);
            af[ks] = *(const short8*)((char*)sA + byte);
        }

        f32x4 acc[4] = {{0.f,0.f,0.f,0.f},{0.f,0.f,0.f,0.f},{0.f,0.f,0.f,0.f},{0.f,0.f,0.f,0.f}};
#pragma unroll
        for (int ks = 0; ks < 8; ++ks)
#pragma unroll
            for (int jt = 0; jt < 4; ++jt)
                acc[jt] = __builtin_amdgcn_mfma_f32_16x16x32_bf16(af[ks], bfr[jt][ks], acc[jt], 0, 0, 0);

        float cl[4], trow[4];
#pragma unroll
        for (int q = 0; q < 4; ++q) {
            int rr = min(r0 + lg * 4 + q, num_con - 1);
            cl[q] = clue[rr];
            float dvq = (float)counts[rr];
            trow[q] = dvq / (dvq + DEG_EPS);
        }
#pragma unroll
        for (int jt = 0; jt < 4; ++jt)
#pragma unroll
            for (int q = 0; q < 4; ++q) {
                float z = fmaxf(acc[jt][q] + trow[q] * bvv[jt] + uc[jt] * cl[q] + b2[jt], 0.0f);
                sZ[buf][(lg * 4 + q) * C2 + w * 64 + jt * 16 + lr] = z;
            }
        __syncthreads();
        {
            int row = tid >> 4;
            const float* zp = &sZ[buf][row * C2 + seg * 16];
            f32x4 z4[4];
            float s = 0.f, s2 = 0.f;
#pragma unroll
            for (int k = 0; k < 4; ++k) {
                z4[k] = *(const f32x4*)(zp + k * 4);
#pragma unroll
                for (int e = 0; e < 4; ++e) { s += z4[k][e]; s2 += z4[k][e] * z4[k][e]; }
            }
#pragma unroll
            for (int m = 1; m < 16; m <<= 1) {
                s  += __shfl_xor(s,  m, 64);
                s2 += __shfl_xor(s2, m, 64);
            }
            float mu = s * (1.0f / HD);
            float var = s2 * (1.0f / HD) - mu * mu;
            float rs = rsqrtf(var + LN_EPS);
            int grow = r0 + row;
            if (grow < num_con) {
                float* gp = out + (long)grow * HD + seg * 16;
#pragma unroll
                for (int k = 0; k < 4; ++k) {
                    f32x4 o;
#pragma unroll
                    for (int e = 0; e < 4; ++e)
                        o[e] = (z4[k][e] - mu) * rs * lw[k][e] + lb[k][e];
                    *(f32x4*)(gp + k * 4) = o;
                }
            }
        }
        buf ^= 1;
    }
}

extern "C" void kernel_launch(void* const* d_in, const int* in_sizes, int n_in,
                              void* d_out, int out_size, void* d_ws, size_t ws_size,
                              hipStream_t stream) {
    const float* x_var = (const float*)d_in[0];
    const int*   src   = (const int*)d_in[1];
    const int*   dst   = (const int*)d_in[2];
    const float* clue  = (const float*)d_in[3];
    // d_in[4] = num_con scalar (derived from out_size instead)
    const float* msg_W = (const float*)d_in[5];
    const float* msg_b = (const float*)d_in[6];
    const float* upd_W = (const float*)d_in[7];
    const float* upd_b = (const float*)d_in[8];
    const float* ln_w  = (const float*)d_in[9];
    const float* ln_b  = (const float*)d_in[10];

    int E = in_sizes[1];
    long n_x = in_sizes[0];
    int n_var = (int)(n_x / HD);
    int num_con = out_size / HD;
    int ntiles = (num_con + 15) / 16;

    char* ws = (char*)d_ws;
    int* counts = (int*)ws;                               // num_con ints
    int* eidx   = (int*)(ws + (((size_t)num_con * 4 + 255) & ~(size_t)255));
    char* after = (char*)(eidx + (size_t)num_con * CAP);  // num_con*CAP ints
    size_t xoff = ((size_t)(after - ws) + 255) & ~(size_t)255;
    unsigned short* xb = (unsigned short*)(ws + xoff);    // n_var*256 bf16
    size_t aoff = (xoff + (size_t)n_var * HD * 2 + 255) & ~(size_t)255;
    unsigned short* agg = (unsigned short*)(ws + aoff);   // num_con*256 bf16
    size_t woff = (aoff + (size_t)num_con * HD * 2 + 255) & ~(size_t)255;
    unsigned short* w12b = (unsigned short*)(ws + woff);  // 256*256 bf16
    float* bvp  = (float*)(w12b + 256 * 256);             // 256 fp32
    float* ucol = bvp + 256;                              // 256 fp32

    int zb = (num_con + 1023) / 1024;
    int xblk = (int)((n_x / 8 + 255) / 256);
    prep_kernel<<<zb + 256 + xblk, 256, 0, stream>>>(
        counts, num_con, msg_W, msg_b, upd_W, w12b, bvp, ucol,
        x_var, xb, n_x, zb);

    fill_kernel<<<(E + 255) / 256, 256, 0, stream>>>(src, dst, counts, eidx, E);

    gather_kernel<<<(num_con + 3) / 4, 256, 0, stream>>>(
        xb, counts, eidx, agg, num_con);

    gfinal_kernel<<<1024, 256, 0, stream>>>(
        agg, counts, clue, w12b, bvp, ucol, upd_b, ln_w, ln_b,
        (float*)d_out, num_con, ntiles);
}